// Round 11
// baseline (1275.341 us; speedup 1.0000x reference)
//
#include <hip/hip_runtime.h>

typedef unsigned int u32;
typedef unsigned short u16;
typedef _Float16 f16;
typedef __attribute__((ext_vector_type(8))) _Float16 f16x8;
typedef __attribute__((ext_vector_type(2))) _Float16 f16x2;
typedef __attribute__((ext_vector_type(4))) float f32x4;

#define NNODES 100000
#define NEDGES 600000
#define CC 16
#define HH 48
#define NL 5

// ---- CSR ws layout (float-sized units), total 4,000,064 floats = 16.0 MB ----
#define OX1   0
#define OX2   1600000
#define OROW  3200000
#define ODEG  3300032
#define OPERM 3400032
#define OSL   4000032
#define WS_CSR_FLOATS    4000064
// ---- fallback (atomic) layout ----
#define FCNT  3200000
#define FSL   3300000
#define WS_ATOM_FLOATS   3300032

// pair-exchange between adjacent lanes (bit0 of lane id)
__device__ __forceinline__ float pair_swap(float v){ return __shfl_xor(v, 1); }

// pack two floats into two f16 halves of a u32 (RNE via scalar casts)
__device__ __forceinline__ u32 pack16(float lo, float hi){
  f16x2 p;
  p[0] = (f16)lo;
  p[1] = (f16)hi;
  u32 r;
  __builtin_memcpy(&r, &p, 4);
  return r;
}

// =================== CSR build ===================
__global__ __launch_bounds__(256) void count_deg(const int* __restrict__ ei, int* __restrict__ deg){
  int e = blockIdx.x * 256 + threadIdx.x;
  if (e >= NEDGES) return;
  atomicAdd(&deg[ei[NEDGES + e]], 1);
}

__global__ __launch_bounds__(1024) void scan_deg(const int* __restrict__ deg, int* __restrict__ rowptr){
  __shared__ int part[1024];
  int t = threadIdx.x;
  const int CH = (NNODES + 1023) / 1024;
  int b = t * CH;
  int e = b + CH < NNODES ? b + CH : NNODES;
  int s = 0;
  for (int i = b; i < e; i++) s += deg[i];
  part[t] = s;
  __syncthreads();
  for (int off = 1; off < 1024; off <<= 1){
    int v = (t >= off) ? part[t - off] : 0;
    __syncthreads();
    part[t] += v;
    __syncthreads();
  }
  int run = (t == 0) ? 0 : part[t - 1];
  for (int i = b; i < e; i++){ rowptr[i] = run; run += deg[i]; }
  if (t == 1023) rowptr[NNODES] = run;
}

__global__ __launch_bounds__(256) void scatter_perm(const int* __restrict__ ei,
    const int* __restrict__ rowptr, int* __restrict__ deg2, int* __restrict__ perm){
  int e = blockIdx.x * 256 + threadIdx.x;
  if (e >= NEDGES) return;
  int d = ei[NEDGES + e];
  int pos = rowptr[d] + atomicAdd(&deg2[d], 1);
  perm[pos] = e;
}

// ====== NodeConv: 4 threads per node stride its CSR edges; shfl-reduce; no atomics ======
__global__ __launch_bounds__(256) void nc_csr4(
    const float* __restrict__ x, const int* __restrict__ ei,
    const float* __restrict__ ang,
    const int* __restrict__ rowptr, const int* __restrict__ perm,
    const float* __restrict__ w0, const float* __restrict__ b0,
    const float* __restrict__ wh, const float* __restrict__ bh,
    float* __restrict__ xout)
{
  int tid = blockIdx.x * 256 + threadIdx.x;
  int n = tid >> 2, j = tid & 3;
  if (n >= NNODES) return;
  int beg = rowptr[n], end = rowptr[n + 1];

  float xd[16];
  {
    const float4* pd = (const float4*)(x + (long)n * 16);
    #pragma unroll
    for (int i = 0; i < 4; i++){ float4 v = pd[i]; xd[4*i]=v.x; xd[4*i+1]=v.y; xd[4*i+2]=v.z; xd[4*i+3]=v.w; }
  }
  float p0[16];
  #pragma unroll
  for (int jj = 0; jj < 16; jj++) p0[jj] = b0[jj];
  #pragma unroll
  for (int k = 0; k < 16; k++){
    float v = xd[k];
    #pragma unroll
    for (int jj = 0; jj < 16; jj++) p0[jj] = fmaf(v, w0[k*16 + jj], p0[jj]);
  }

  float sum[16];
  #pragma unroll
  for (int jj = 0; jj < 16; jj++) sum[jj] = 0.f;

  for (int idx = beg + j; idx < end; idx += 4){
    int e = perm[idx];
    int s = ei[e];
    float a_ = ang[e];
    float xs[16];
    {
      const float4* ps = (const float4*)(x + (long)s * 16);
      #pragma unroll
      for (int i = 0; i < 4; i++){ float4 v = ps[i]; xs[4*i]=v.x; xs[4*i+1]=v.y; xs[4*i+2]=v.z; xs[4*i+3]=v.w; }
    }
    float acc[16], h[16];
    #pragma unroll
    for (int jj = 0; jj < 16; jj++) acc[jj] = p0[jj];
    #pragma unroll
    for (int k = 0; k < 16; k++){
      float v = xs[k];
      #pragma unroll
      for (int jj = 0; jj < 16; jj++) acc[jj] = fmaf(v, w0[(16 + k)*16 + jj], acc[jj]);
    }
    #pragma unroll
    for (int jj = 0; jj < 16; jj++) h[jj] = fmaxf(fmaf(a_, w0[32*16 + jj], acc[jj]), 0.f);

    for (int l = 0; l < NL; l++){
      const float* w = wh + l * 256;
      const float* b = bh + l * 16;
      #pragma unroll
      for (int jj = 0; jj < 16; jj++) acc[jj] = b[jj];
      #pragma unroll
      for (int k = 0; k < 16; k++){
        float v = h[k];
        #pragma unroll
        for (int jj = 0; jj < 16; jj++) acc[jj] = fmaf(v, w[k*16 + jj], acc[jj]);
      }
      #pragma unroll
      for (int jj = 0; jj < 16; jj++) h[jj] = fmaxf(acc[jj], 0.f);
    }
    #pragma unroll
    for (int jj = 0; jj < 16; jj++) sum[jj] += h[jj];
  }

  // reduce the 4 per-node partials (lanes differ in bits 0..1 of lane id)
  #pragma unroll
  for (int jj = 0; jj < 16; jj++){
    sum[jj] += __shfl_xor(sum[jj], 1);
    sum[jj] += __shfl_xor(sum[jj], 2);
  }
  if (j == 0){
    float inv = 1.f / fmaxf((float)(end - beg), 1.f);
    float4* po = (float4*)(xout + (long)n * 16);
    #pragma unroll
    for (int i = 0; i < 4; i++){
      float4 v; v.x = sum[4*i]*inv; v.y = sum[4*i+1]*inv; v.z = sum[4*i+2]*inv; v.w = sum[4*i+3]*inv;
      po[i] = v;
    }
  }
}

// =================== fallback atomic NodeConv (r7, proven) ===================
__global__ __launch_bounds__(256) void nc_kernel(
    const float* __restrict__ x, const int* __restrict__ ei,
    const float* __restrict__ ang,
    const float* __restrict__ w0, const float* __restrict__ b0,
    const float* __restrict__ wh, const float* __restrict__ bh,
    float* __restrict__ agg, float* __restrict__ cnt)
{
  int e = blockIdx.x * 256 + threadIdx.x;
  if (e >= NEDGES) return;
  int s = ei[e];
  int d = ei[NEDGES + e];
  float in[33];
  {
    const float4* pd = (const float4*)(x + (long)d * 16);
    const float4* ps = (const float4*)(x + (long)s * 16);
    #pragma unroll
    for (int i = 0; i < 4; i++){ float4 v = pd[i]; in[4*i]=v.x; in[4*i+1]=v.y; in[4*i+2]=v.z; in[4*i+3]=v.w; }
    #pragma unroll
    for (int i = 0; i < 4; i++){ float4 v = ps[i]; in[16+4*i]=v.x; in[16+4*i+1]=v.y; in[16+4*i+2]=v.z; in[16+4*i+3]=v.w; }
  }
  in[32] = ang[e];
  float h[16], acc[16];
  #pragma unroll
  for (int j = 0; j < 16; j++) acc[j] = b0[j];
  #pragma unroll
  for (int k = 0; k < 33; k++){
    float v = in[k];
    #pragma unroll
    for (int j = 0; j < 16; j++) acc[j] = fmaf(v, w0[k*16+j], acc[j]);
  }
  #pragma unroll
  for (int j = 0; j < 16; j++) h[j] = fmaxf(acc[j], 0.f);
  for (int l = 0; l < NL; l++){
    const float* w = wh + l * 256;
    const float* b = bh + l * 16;
    #pragma unroll
    for (int j = 0; j < 16; j++) acc[j] = b[j];
    #pragma unroll
    for (int k = 0; k < 16; k++){
      float v = h[k];
      #pragma unroll
      for (int j = 0; j < 16; j++) acc[j] = fmaf(v, w[k*16+j], acc[j]);
    }
    #pragma unroll
    for (int j = 0; j < 16; j++) h[j] = fmaxf(acc[j], 0.f);
  }
  float* ag = agg + (long)d * 16;
  #pragma unroll
  for (int j = 0; j < 16; j++) atomicAdd(ag + j, h[j]);
  atomicAdd(cnt + d, 1.0f);
}

__global__ __launch_bounds__(256) void node_fin(float* __restrict__ x, const float* __restrict__ cnt)
{
  int i = blockIdx.x * 256 + threadIdx.x;
  if (i >= NNODES * CC) return;
  float c = cnt[i >> 4];
  x[i] = x[i] / fmaxf(c, 1.f);
}

// ============================================================================
// Fused EdgeConv1+EdgeConv2 via MFMA. XOR-swizzled LDS (8-half chunks, stride 64).
// Row pairs (2k,2k+1) = (f1,f2) of edge k: pairs land in the SAME lane's C regs
// (row=4q+reg) -> fe/side/final-dots entirely in registers. No EF pane.
// LDS = 32768 (H) + 12288 (W dbuf) = 45056 B -> 3 blocks/CU.
// ============================================================================
__global__ __launch_bounds__(256) void ec_mfma(
    const float* __restrict__ x1, const float* __restrict__ x2,
    const int* __restrict__ ei, const float* __restrict__ act,
    const float* __restrict__ e1w0, const float* __restrict__ e1b0,
    const float* __restrict__ e1wh, const float* __restrict__ e1bh,
    const float* __restrict__ e1wc, const float* __restrict__ e1bc,
    const float* __restrict__ e2w0, const float* __restrict__ e2b0,
    const float* __restrict__ e2wh, const float* __restrict__ e2bh,
    const float* __restrict__ e2wc, const float* __restrict__ e2bc,
    float* __restrict__ out, float* __restrict__ slacc)
{
  __shared__ __align__(16) f16 Hb[256 * 64];     // 32768 B
  __shared__ __align__(16) f16 Wb[2][48 * 64];   // 12288 B

  const int t = threadIdx.x;
  const int lane = t & 63;
  const int q = lane >> 4, n15 = lane & 15;
  const int wrow = (t >> 6) << 6;
  const int ebase = blockIdx.x * 128;
  int e = ebase + (t >> 1);
  if (e >= NEDGES) e = NEDGES - 1;
  const int o = t & 1;
  const int s = ei[e], d = ei[NEDGES + e];
  const int nA = o ? s : d;                      // row 2k: [x_d|x_s]=f1 ; 2k+1: [x_s|x_d]=f2
  const int nB = o ? d : s;

  float wc2a[3], wc2b[3];
  #pragma unroll
  for (int nt = 0; nt < 3; nt++){ wc2a[nt] = e2wc[16*nt + n15]; wc2b[nt] = e2wc[48 + 16*nt + n15]; }
  float outAcc[4][2];
  #pragma unroll
  for (int mt = 0; mt < 4; mt++){ outAcc[mt][0] = 0.f; outAcc[mt][1] = 0.f; }
  float side = 0.f;

  // swizzled addressing: element (row,k) -> row*64 + ((k/8 ^ row%8)*8 + k%8)
  auto stage_w = [&](const float* w, int Kl, int buf){
    f16* dst = Wb[buf];
    for (int idx = t; idx < 48 * Kl; idx += 256){
      int k = idx / 48, n = idx - 48 * k;
      dst[(n << 6) + ((((k >> 3) ^ (n & 7)) << 3) | (k & 7))] = (f16)w[idx];
    }
    for (int idx = t; idx < 48 * (64 - Kl); idx += 256){
      int k = Kl + idx / 48, n = idx - (idx / 48) * 48;
      dst[(n << 6) + ((((k >> 3) ^ (n & 7)) << 3) | (k & 7))] = (f16)0.f;
    }
  };

  auto stage_x = [&](const float* x){
    const float4* pa = (const float4*)(x + (long)nA * 16);
    const float4* pb = (const float4*)(x + (long)nB * 16);
    float4 v[4] = {pa[0], pa[1], pa[2], pa[3]};
    float4 w[4] = {pb[0], pb[1], pb[2], pb[3]};
    f16* hp = &Hb[t << 6];
    int sw = t & 7;
    #pragma unroll
    for (int c = 0; c < 2; c++){
      f16x8 h;
      float4 a = v[2*c], b = v[2*c+1];
      h[0]=(f16)a.x; h[1]=(f16)a.y; h[2]=(f16)a.z; h[3]=(f16)a.w;
      h[4]=(f16)b.x; h[5]=(f16)b.y; h[6]=(f16)b.z; h[7]=(f16)b.w;
      *(f16x8*)(hp + ((c ^ sw) << 3)) = h;
    }
    #pragma unroll
    for (int c = 2; c < 4; c++){
      f16x8 h;
      float4 a = w[2*(c-2)], b = w[2*(c-2)+1];
      h[0]=(f16)a.x; h[1]=(f16)a.y; h[2]=(f16)a.z; h[3]=(f16)a.w;
      h[4]=(f16)b.x; h[5]=(f16)b.y; h[6]=(f16)b.z; h[7]=(f16)b.w;
      *(f16x8*)(hp + ((c ^ sw) << 3)) = h;
    }
    f16x8 z = {};
    #pragma unroll
    for (int c = 4; c < 8; c++) *(f16x8*)(hp + ((c ^ sw) << 3)) = z;
  };

  // one dense layer. mode 0: hidden (relu, write H). mode 1: conv0-final (relu, fe+side, write fe).
  // mode 2: conv0-combine (no relu, ef-dot, no write). mode 3: conv1-final (relu, fe2+side, fe-dot).
  auto layer = [&](int buf, const float* bias, int mode){
    f32x4 C[4][3];
    #pragma unroll
    for (int mt = 0; mt < 4; mt++)
      #pragma unroll
      for (int nt = 0; nt < 3; nt++)
        C[mt][nt] = (f32x4){0.f, 0.f, 0.f, 0.f};
    #pragma unroll
    for (int ks = 0; ks < 2; ks++){
      int c = (ks << 2) + q;
      f16x8 Bf[3];
      #pragma unroll
      for (int nt = 0; nt < 3; nt++){
        int n = 16*nt + n15;
        Bf[nt] = *(const f16x8*)&Wb[buf][(n << 6) + ((c ^ (n & 7)) << 3)];
      }
      #pragma unroll
      for (int mt = 0; mt < 4; mt++){
        int r = wrow + (mt << 4) + n15;
        f16x8 Af = *(const f16x8*)&Hb[(r << 6) + ((c ^ (r & 7)) << 3)];
        #pragma unroll
        for (int nt = 0; nt < 3; nt++)
          C[mt][nt] = __builtin_amdgcn_mfma_f32_16x16x32_f16(Af, Bf[nt], C[mt][nt], 0, 0, 0);
      }
    }
    #pragma unroll
    for (int nt = 0; nt < 3; nt++){
      int col = 16*nt + n15;
      float bv = bias[col];
      int ch = col >> 3, co = col & 7;     // col chunk/offset (co even for even n15)
      #pragma unroll
      for (int mt = 0; mt < 4; mt++){
        int rbase = wrow + (mt << 4) + (q << 2);
        if (mode == 0){
          #pragma unroll
          for (int reg = 0; reg < 4; reg++){
            float v = fmaxf(C[mt][nt][reg] + bv, 0.f);
            float pv = pair_swap(v);
            if (!(n15 & 1)){
              int r = rbase + reg;
              *(u32*)&Hb[(r << 6) + ((ch ^ (r & 7)) << 3) + co] = pack16(v, pv);
            }
          }
        } else if (mode == 1){
          #pragma unroll
          for (int p = 0; p < 2; p++){
            float v0 = fmaxf(C[mt][nt][2*p]   + bv, 0.f);
            float v1 = fmaxf(C[mt][nt][2*p+1] + bv, 0.f);
            int ed = ebase + (rbase >> 1) + p;
            float dd = v0 - v1;
            if (ed < NEDGES) side += dd * dd;
            float fe = 0.5f * (v0 + v1);
            float pfe = pair_swap(fe);
            if (!(n15 & 1)){
              u32 pk = pack16(fe, pfe);
              #pragma unroll
              for (int rr = 0; rr < 2; rr++){
                int r = rbase + 2*p + rr;
                *(u32*)&Hb[(r << 6) + ((ch ^ (r & 7)) << 3) + co] = pk;
              }
            }
          }
        } else if (mode == 2){
          #pragma unroll
          for (int p = 0; p < 2; p++){
            float v = C[mt][nt][2*p] + bv;               // no relu; pair rows identical
            outAcc[mt][p] = fmaf(v, wc2b[nt], outAcc[mt][p]);
          }
        } else {
          #pragma unroll
          for (int p = 0; p < 2; p++){
            float v0 = fmaxf(C[mt][nt][2*p]   + bv, 0.f);
            float v1 = fmaxf(C[mt][nt][2*p+1] + bv, 0.f);
            int ed = ebase + (rbase >> 1) + p;
            float dd = v0 - v1;
            if (ed < NEDGES) side += dd * dd;
            float fe = 0.5f * (v0 + v1);
            outAcc[mt][p] = fmaf(fe, wc2a[nt], outAcc[mt][p]);
          }
        }
      }
    }
  };

  // ================= conv0 (EdgeConv1 on x1) =================
  stage_x(x1);
  Hb[(t << 6) + ((6 ^ (t & 7)) << 3)] = (f16)act[e];   // col 48 = action
  stage_w(e1w0, 32, 0);
  for (int l = 0; l < 7; l++){
    __syncthreads();
    if (l < 5)       stage_w(e1wh + l * 2304, 48, (l + 1) & 1);
    else if (l == 5) stage_w(e1wc, 49, 0);             // combine weights (49x48)
    const float* bias = (l == 0) ? e1b0 : (l <= 5 ? e1bh + (l - 1) * 48 : e1bc);
    layer(l & 1, bias, (l < 5) ? 0 : (l == 5 ? 1 : 2));
  }

  // ================= conv1 (EdgeConv2 on x2) =================
  __syncthreads();                                     // conv0 combine reads done
  stage_x(x2);
  stage_w(e2w0, 32, 0);
  for (int l = 0; l < 6; l++){
    __syncthreads();
    if (l < 5) stage_w(e2wh + l * 2304, 48, (l + 1) & 1);
    const float* bias = (l == 0) ? e2b0 : e2bh + (l - 1) * 48;
    layer(l & 1, bias, (l < 5) ? 0 : 3);
  }

  // ================= epilogue: out = bc2 + sum_cols(fe2*wc2a + ef*wc2b) =================
  float bc2v = e2bc[0];
  #pragma unroll
  for (int mt = 0; mt < 4; mt++)
    #pragma unroll
    for (int p = 0; p < 2; p++){
      float v = outAcc[mt][p];
      v += __shfl_xor(v, 1); v += __shfl_xor(v, 2);
      v += __shfl_xor(v, 4); v += __shfl_xor(v, 8);
      if (n15 == 0){
        int ed = ebase + ((wrow + (mt << 4) + (q << 2)) >> 1) + p;
        if (ed < NEDGES) out[ed] = v + bc2v;
      }
    }
  float sv = side;
  #pragma unroll
  for (int off = 32; off; off >>= 1) sv += __shfl_down(sv, off);
  if (lane == 0) atomicAdd(slacc, sv);
}

// each (edge,col) counted once per conv: S = S1+S2 ; loss = S/(2*48E) = S/57.6e6
__global__ void fin_sl(const float* __restrict__ slacc, float* __restrict__ out){
  if (threadIdx.x == 0 && blockIdx.x == 0)
    out[NEDGES] = slacc[0] * (1.0f / 57600000.0f);
}

// ================= launch ==================
extern "C" void kernel_launch(void* const* d_in, const int* in_sizes, int n_in,
                              void* d_out, int out_size, void* d_ws, size_t ws_size,
                              hipStream_t stream)
{
  if (n_in < 25) return;

  const float* nf  = (const float*)d_in[0];
  const int*   ei  = (const int*)d_in[1];
  const float* ang = (const float*)d_in[2];
  const float* act = (const float*)d_in[4];
  const float* nc1_w0 = (const float*)d_in[5];
  const float* nc1_b0 = (const float*)d_in[6];
  const float* nc1_wh = (const float*)d_in[7];
  const float* nc1_bh = (const float*)d_in[8];
  const float* nc2_w0 = (const float*)d_in[9];
  const float* nc2_b0 = (const float*)d_in[10];
  const float* nc2_wh = (const float*)d_in[11];
  const float* nc2_bh = (const float*)d_in[12];
  const float* e1w0 = (const float*)d_in[13];
  const float* e1b0 = (const float*)d_in[14];
  const float* e1wh = (const float*)d_in[15];
  const float* e1bh = (const float*)d_in[16];
  const float* e1wc = (const float*)d_in[17];
  const float* e1bc = (const float*)d_in[18];
  const float* e2w0 = (const float*)d_in[19];
  const float* e2b0 = (const float*)d_in[20];
  const float* e2wh = (const float*)d_in[21];
  const float* e2bh = (const float*)d_in[22];
  const float* e2wc = (const float*)d_in[23];
  const float* e2bc = (const float*)d_in[24];

  float* ws  = (float*)d_ws;
  float* out = (float*)d_out;
  const int eb  = (NEDGES + 255) / 256;        // 2344
  const int ecb = (NEDGES + 127) / 128;        // 4688
  const int nb4 = (NNODES * 4 + 255) / 256;    // 1563

  if (ws_size >= (size_t)WS_CSR_FLOATS * sizeof(float)){
    float* x1 = ws + OX1;
    float* x2 = ws + OX2;
    int* rowptr = (int*)(ws + OROW);
    int* deg    = (int*)(ws + ODEG);
    int* perm   = (int*)(ws + OPERM);
    float* sl   = ws + OSL;

    (void)hipMemsetAsync(deg, 0, (size_t)NNODES * sizeof(int), stream);
    (void)hipMemsetAsync(sl, 0, sizeof(float), stream);

    hipLaunchKernelGGL(count_deg, dim3(eb), dim3(256), 0, stream, ei, deg);
    hipLaunchKernelGGL(scan_deg, dim3(1), dim3(1024), 0, stream, deg, rowptr);
    (void)hipMemsetAsync(deg, 0, (size_t)NNODES * sizeof(int), stream);
    hipLaunchKernelGGL(scatter_perm, dim3(eb), dim3(256), 0, stream, ei, rowptr, deg, perm);

    hipLaunchKernelGGL(nc_csr4, dim3(nb4), dim3(256), 0, stream,
        nf, ei, ang, rowptr, perm, nc1_w0, nc1_b0, nc1_wh, nc1_bh, x1);
    hipLaunchKernelGGL(nc_csr4, dim3(nb4), dim3(256), 0, stream,
        x1, ei, ang, rowptr, perm, nc2_w0, nc2_b0, nc2_wh, nc2_bh, x2);

    hipLaunchKernelGGL(ec_mfma, dim3(ecb), dim3(256), 0, stream,
        x1, x2, ei, act,
        e1w0, e1b0, e1wh, e1bh, e1wc, e1bc,
        e2w0, e2b0, e2wh, e2bh, e2wc, e2bc,
        out, sl);
    hipLaunchKernelGGL(fin_sl, dim3(1), dim3(64), 0, stream, sl, out);
  } else if (ws_size >= (size_t)WS_ATOM_FLOATS * sizeof(float)){
    float* x1  = ws + OX1;
    float* x2  = ws + OX2;
    float* cnt = ws + FCNT;
    float* sl  = ws + FSL;
    const int nb = (NNODES * CC + 255) / 256;

    (void)hipMemsetAsync(ws, 0, (size_t)WS_ATOM_FLOATS * sizeof(float), stream);
    hipLaunchKernelGGL(nc_kernel, dim3(eb), dim3(256), 0, stream,
        nf, ei, ang, nc1_w0, nc1_b0, nc1_wh, nc1_bh, x1, cnt);
    hipLaunchKernelGGL(node_fin, dim3(nb), dim3(256), 0, stream, x1, cnt);
    (void)hipMemsetAsync(cnt, 0, (size_t)NNODES * sizeof(float), stream);
    hipLaunchKernelGGL(nc_kernel, dim3(eb), dim3(256), 0, stream,
        x1, ei, ang, nc2_w0, nc2_b0, nc2_wh, nc2_bh, x2, cnt);
    hipLaunchKernelGGL(node_fin, dim3(nb), dim3(256), 0, stream, x2, cnt);
    hipLaunchKernelGGL(ec_mfma, dim3(ecb), dim3(256), 0, stream,
        x1, x2, ei, act,
        e1w0, e1b0, e1wh, e1bh, e1wc, e1bc,
        e2w0, e2b0, e2wh, e2bh, e2wc, e2bc,
        out, sl);
    hipLaunchKernelGGL(fin_sl, dim3(1), dim3(64), 0, stream, sl, out);
  }
}

// Round 12
// 1119.048 us; speedup vs baseline: 1.1397x; 1.1397x over previous
//
#include <hip/hip_runtime.h>

typedef unsigned int u32;
typedef _Float16 f16;
typedef __attribute__((ext_vector_type(8))) _Float16 f16x8;
typedef __attribute__((ext_vector_type(4))) _Float16 f16x4;
typedef __attribute__((ext_vector_type(4))) float f32x4;

#define NNODES 100000
#define NEDGES 600000
#define CC 16
#define HH 48
#define NL 5

// ---- CSR ws layout (float-sized units), total 4,000,064 floats = 16.0 MB ----
#define OX1   0
#define OX2   1600000
#define OROW  3200000
#define ODEG  3300032
#define OPERM 3400032
#define OSL   4000032
#define WS_CSR_FLOATS    4000064
// ---- fallback (atomic) layout ----
#define FCNT  3200000
#define FSL   3300000
#define WS_ATOM_FLOATS   3300032

// =================== CSR build ===================
__global__ __launch_bounds__(256) void count_deg(const int* __restrict__ ei, int* __restrict__ deg){
  int e = blockIdx.x * 256 + threadIdx.x;
  if (e >= NEDGES) return;
  atomicAdd(&deg[ei[NEDGES + e]], 1);
}

__global__ __launch_bounds__(1024) void scan_deg(const int* __restrict__ deg, int* __restrict__ rowptr){
  __shared__ int part[1024];
  int t = threadIdx.x;
  const int CH = (NNODES + 1023) / 1024;
  int b = t * CH;
  int e = b + CH < NNODES ? b + CH : NNODES;
  int s = 0;
  for (int i = b; i < e; i++) s += deg[i];
  part[t] = s;
  __syncthreads();
  for (int off = 1; off < 1024; off <<= 1){
    int v = (t >= off) ? part[t - off] : 0;
    __syncthreads();
    part[t] += v;
    __syncthreads();
  }
  int run = (t == 0) ? 0 : part[t - 1];
  for (int i = b; i < e; i++){ rowptr[i] = run; run += deg[i]; }
  if (t == 1023) rowptr[NNODES] = run;
}

__global__ __launch_bounds__(256) void scatter_perm(const int* __restrict__ ei,
    const int* __restrict__ rowptr, int* __restrict__ deg2, int* __restrict__ perm){
  int e = blockIdx.x * 256 + threadIdx.x;
  if (e >= NEDGES) return;
  int d = ei[NEDGES + e];
  int pos = rowptr[d] + atomicAdd(&deg2[d], 1);
  perm[pos] = e;
}

// ====== NodeConv: 4 threads per node stride its CSR edges; shfl-reduce; no atomics ======
__global__ __launch_bounds__(256) void nc_csr4(
    const float* __restrict__ x, const int* __restrict__ ei,
    const float* __restrict__ ang,
    const int* __restrict__ rowptr, const int* __restrict__ perm,
    const float* __restrict__ w0, const float* __restrict__ b0,
    const float* __restrict__ wh, const float* __restrict__ bh,
    float* __restrict__ xout)
{
  int tid = blockIdx.x * 256 + threadIdx.x;
  int n = tid >> 2, j = tid & 3;
  if (n >= NNODES) return;
  int beg = rowptr[n], end = rowptr[n + 1];

  float xd[16];
  {
    const float4* pd = (const float4*)(x + (long)n * 16);
    #pragma unroll
    for (int i = 0; i < 4; i++){ float4 v = pd[i]; xd[4*i]=v.x; xd[4*i+1]=v.y; xd[4*i+2]=v.z; xd[4*i+3]=v.w; }
  }
  float p0[16];
  #pragma unroll
  for (int jj = 0; jj < 16; jj++) p0[jj] = b0[jj];
  #pragma unroll
  for (int k = 0; k < 16; k++){
    float v = xd[k];
    #pragma unroll
    for (int jj = 0; jj < 16; jj++) p0[jj] = fmaf(v, w0[k*16 + jj], p0[jj]);
  }

  float sum[16];
  #pragma unroll
  for (int jj = 0; jj < 16; jj++) sum[jj] = 0.f;

  for (int idx = beg + j; idx < end; idx += 4){
    int e = perm[idx];
    int s = ei[e];
    float a_ = ang[e];
    float xs[16];
    {
      const float4* ps = (const float4*)(x + (long)s * 16);
      #pragma unroll
      for (int i = 0; i < 4; i++){ float4 v = ps[i]; xs[4*i]=v.x; xs[4*i+1]=v.y; xs[4*i+2]=v.z; xs[4*i+3]=v.w; }
    }
    float acc[16], h[16];
    #pragma unroll
    for (int jj = 0; jj < 16; jj++) acc[jj] = p0[jj];
    #pragma unroll
    for (int k = 0; k < 16; k++){
      float v = xs[k];
      #pragma unroll
      for (int jj = 0; jj < 16; jj++) acc[jj] = fmaf(v, w0[(16 + k)*16 + jj], acc[jj]);
    }
    #pragma unroll
    for (int jj = 0; jj < 16; jj++) h[jj] = fmaxf(fmaf(a_, w0[32*16 + jj], acc[jj]), 0.f);

    for (int l = 0; l < NL; l++){
      const float* w = wh + l * 256;
      const float* b = bh + l * 16;
      #pragma unroll
      for (int jj = 0; jj < 16; jj++) acc[jj] = b[jj];
      #pragma unroll
      for (int k = 0; k < 16; k++){
        float v = h[k];
        #pragma unroll
        for (int jj = 0; jj < 16; jj++) acc[jj] = fmaf(v, w[k*16 + jj], acc[jj]);
      }
      #pragma unroll
      for (int jj = 0; jj < 16; jj++) h[jj] = fmaxf(acc[jj], 0.f);
    }
    #pragma unroll
    for (int jj = 0; jj < 16; jj++) sum[jj] += h[jj];
  }

  #pragma unroll
  for (int jj = 0; jj < 16; jj++){
    sum[jj] += __shfl_xor(sum[jj], 1);
    sum[jj] += __shfl_xor(sum[jj], 2);
  }
  if (j == 0){
    float inv = 1.f / fmaxf((float)(end - beg), 1.f);
    float4* po = (float4*)(xout + (long)n * 16);
    #pragma unroll
    for (int i = 0; i < 4; i++){
      float4 v; v.x = sum[4*i]*inv; v.y = sum[4*i+1]*inv; v.z = sum[4*i+2]*inv; v.w = sum[4*i+3]*inv;
      po[i] = v;
    }
  }
}

// =================== fallback atomic NodeConv (r7, proven) ===================
__global__ __launch_bounds__(256) void nc_kernel(
    const float* __restrict__ x, const int* __restrict__ ei,
    const float* __restrict__ ang,
    const float* __restrict__ w0, const float* __restrict__ b0,
    const float* __restrict__ wh, const float* __restrict__ bh,
    float* __restrict__ agg, float* __restrict__ cnt)
{
  int e = blockIdx.x * 256 + threadIdx.x;
  if (e >= NEDGES) return;
  int s = ei[e];
  int d = ei[NEDGES + e];
  float in[33];
  {
    const float4* pd = (const float4*)(x + (long)d * 16);
    const float4* ps = (const float4*)(x + (long)s * 16);
    #pragma unroll
    for (int i = 0; i < 4; i++){ float4 v = pd[i]; in[4*i]=v.x; in[4*i+1]=v.y; in[4*i+2]=v.z; in[4*i+3]=v.w; }
    #pragma unroll
    for (int i = 0; i < 4; i++){ float4 v = ps[i]; in[16+4*i]=v.x; in[16+4*i+1]=v.y; in[16+4*i+2]=v.z; in[16+4*i+3]=v.w; }
  }
  in[32] = ang[e];
  float h[16], acc[16];
  #pragma unroll
  for (int j = 0; j < 16; j++) acc[j] = b0[j];
  #pragma unroll
  for (int k = 0; k < 33; k++){
    float v = in[k];
    #pragma unroll
    for (int j = 0; j < 16; j++) acc[j] = fmaf(v, w0[k*16+j], acc[j]);
  }
  #pragma unroll
  for (int j = 0; j < 16; j++) h[j] = fmaxf(acc[j], 0.f);
  for (int l = 0; l < NL; l++){
    const float* w = wh + l * 256;
    const float* b = bh + l * 16;
    #pragma unroll
    for (int j = 0; j < 16; j++) acc[j] = b[j];
    #pragma unroll
    for (int k = 0; k < 16; k++){
      float v = h[k];
      #pragma unroll
      for (int j = 0; j < 16; j++) acc[j] = fmaf(v, w[k*16+j], acc[j]);
    }
    #pragma unroll
    for (int j = 0; j < 16; j++) h[j] = fmaxf(acc[j], 0.f);
  }
  float* ag = agg + (long)d * 16;
  #pragma unroll
  for (int j = 0; j < 16; j++) atomicAdd(ag + j, h[j]);
  atomicAdd(cnt + d, 1.0f);
}

__global__ __launch_bounds__(256) void node_fin(float* __restrict__ x, const float* __restrict__ cnt)
{
  int i = blockIdx.x * 256 + threadIdx.x;
  if (i >= NNODES * CC) return;
  float c = cnt[i >> 4];
  x[i] = x[i] / fmaxf(c, 1.f);
}

// ============================================================================
// Fused EdgeConv1+EdgeConv2, MFMA, persistent-weight / wave-private-row design.
// Tile = 64 edges (128 H rows: f1 rows 0..63, f2 rows 64..127). 9375 blocks, no tail.
// Roles: A = W-pane (m=channel), B = H rows (n=edge) -> D[row=4q+reg]=channel,
// D[col=lane&15]=edge. Epilogue: in-lane relu+pack, b64 LDS writes, bias via C-init.
// Wave w owns rows [w*16, w*16+16) and [64+w*16, ...): NO per-layer barriers.
// Weights staged once per conv (2 stagings/block). LDS = 16384+43008+2496 = 61888 B.
// Swizzle identical to r11 (numerically verified): elem (row,k) -> row*64 +
// ((k/8 ^ row%8)*8 | k%8).
// ============================================================================
__global__ __launch_bounds__(256) void ec_mfma(
    const float* __restrict__ x1, const float* __restrict__ x2,
    const int* __restrict__ ei, const float* __restrict__ act,
    const float* __restrict__ e1w0, const float* __restrict__ e1b0,
    const float* __restrict__ e1wh, const float* __restrict__ e1bh,
    const float* __restrict__ e1wc, const float* __restrict__ e1bc,
    const float* __restrict__ e2w0, const float* __restrict__ e2b0,
    const float* __restrict__ e2wh, const float* __restrict__ e2bh,
    const float* __restrict__ e2wc, const float* __restrict__ e2bc,
    float* __restrict__ out, float* __restrict__ slacc)
{
  __shared__ __align__(16) f16 Hb[128 * 64];      // 16384 B
  __shared__ __align__(16) f16 Wp[7 * 3072];      // 43008 B
  __shared__ float biasP[624];                    // 2496 B

  const int t = threadIdx.x;
  const int lane = t & 63;
  const int wv = t >> 6;                 // wave 0..3
  const int q = lane >> 4, n15 = lane & 15;
  const int ebase = blockIdx.x * 64;
  const int eL = ebase + wv * 16 + n15;  // this lane's edge (D-col identity)

  // ---- per-lane constants (global, L2-resident; issued early) ----
  const float aL = act[eL];
  const float bc2v = e2bc[0];
  float4 wc1r[3], wcA[3], wcB[3];
  #pragma unroll
  for (int wt = 0; wt < 3; wt++){
    wc1r[wt] = *(const float4*)&e1wc[2304 + wt*16 + 4*q];   // wc1 action row 48
    wcA[wt]  = *(const float4*)&e2wc[wt*16 + 4*q];          // wc2[0:48]
    wcB[wt]  = *(const float4*)&e2wc[48 + wt*16 + 4*q];     // wc2[48:96]
  }

  // ---- staging: W^T pane (rows=channel, k padded to 64, swizzled) ----
  auto stage_w = [&](const float* w, int Kl, f16* dst){
    for (int idx = t; idx < 48 * Kl; idx += 256){
      int k = idx / 48, n = idx - 48 * k;
      dst[(n << 6) + ((((k >> 3) ^ (n & 7)) << 3) | (k & 7))] = (f16)w[idx];
    }
    for (int idx = t; idx < 48 * (64 - Kl); idx += 256){
      int k = Kl + idx / 48, n = idx - (idx / 48) * 48;
      dst[(n << 6) + ((((k >> 3) ^ (n & 7)) << 3) | (k & 7))] = (f16)0.f;
    }
  };
  // ---- staging: H rows (2 threads/row; zero cols 48..63) ----
  auto stage_x = [&](const float* x){
    int row = t >> 1, half = t & 1;
    int eb = ebase + (row & 63);
    int s = ei[eb], dn = ei[NEDGES + eb];
    int node = ((half ^ (row >> 6)) & 1) ? s : dn;  // f1=[x_d|x_s], f2=[x_s|x_d]
    const float4* p = (const float4*)(x + (long)node * 16);
    float4 v0 = p[0], v1 = p[1], v2 = p[2], v3 = p[3];
    f16* hp = &Hb[row << 6];
    int rs = row & 7;
    f16x8 h;
    h[0]=(f16)v0.x; h[1]=(f16)v0.y; h[2]=(f16)v0.z; h[3]=(f16)v0.w;
    h[4]=(f16)v1.x; h[5]=(f16)v1.y; h[6]=(f16)v1.z; h[7]=(f16)v1.w;
    *(f16x8*)&hp[((2*half) ^ rs) << 3] = h;
    h[0]=(f16)v2.x; h[1]=(f16)v2.y; h[2]=(f16)v2.z; h[3]=(f16)v2.w;
    h[4]=(f16)v3.x; h[5]=(f16)v3.y; h[6]=(f16)v3.z; h[7]=(f16)v3.w;
    *(f16x8*)&hp[((2*half + 1) ^ rs) << 3] = h;
    if (half){                                     // zero k 48..63 (chunks 6,7)
      f16x8 z = {};
      *(f16x8*)&hp[(6 ^ rs) << 3] = z;
      *(f16x8*)&hp[(7 ^ rs) << 3] = z;
    }
  };

  float ef[3][4];
  float side = 0.f;
  float outAcc = 0.f;

  // one layer. mode 0: hidden(relu->H). 1: conv1-final(relu,fe+side->H f1 rows).
  // 2: combine(no relu, ef=C+act*wc1r). 3: conv2-final(relu,fe2+side,out dot).
  auto layer = [&](int p, int bo, int nks, int mode){
    const f16* W = &Wp[p * 3072];
    const int nEt = (mode == 2) ? 1 : 2;
    f32x4 C[3][2];
    #pragma unroll
    for (int wt = 0; wt < 3; wt++){
      float4 b4 = *(const float4*)&biasP[bo + wt*16 + 4*q];
      C[wt][0] = (f32x4){b4.x, b4.y, b4.z, b4.w};
      C[wt][1] = C[wt][0];
    }
    for (int ks = 0; ks < nks; ks++){
      int c = ks*4 + q;
      f16x8 Af[3];
      #pragma unroll
      for (int wt = 0; wt < 3; wt++){
        int r = wt*16 + n15;
        Af[wt] = *(const f16x8*)&W[(r << 6) + ((c ^ (r & 7)) << 3)];
      }
      for (int et = 0; et < nEt; et++){
        int r = (et << 6) + wv*16 + n15;
        f16x8 Bf = *(const f16x8*)&Hb[(r << 6) + ((c ^ (r & 7)) << 3)];
        #pragma unroll
        for (int wt = 0; wt < 3; wt++)
          C[wt][et] = __builtin_amdgcn_mfma_f32_16x16x32_f16(Af[wt], Bf, C[wt][et], 0, 0, 0);
      }
    }
    if (mode == 0){
      #pragma unroll
      for (int et = 0; et < 2; et++){
        int r = (et << 6) + wv*16 + n15;
        #pragma unroll
        for (int wt = 0; wt < 3; wt++){
          f16x4 pk;
          #pragma unroll
          for (int reg = 0; reg < 4; reg++) pk[reg] = (f16)fmaxf(C[wt][et][reg], 0.f);
          int col = wt*16 + 4*q;
          *(f16x4*)&Hb[(r << 6) + ((((col >> 3) ^ (r & 7)) << 3) | (col & 7))] = pk;
        }
      }
    } else if (mode == 1){
      int r = wv*16 + n15;                         // write fe to f1 rows only
      #pragma unroll
      for (int wt = 0; wt < 3; wt++){
        f16x4 pk;
        #pragma unroll
        for (int reg = 0; reg < 4; reg++){
          float v1 = fmaxf(C[wt][0][reg], 0.f);
          float v2 = fmaxf(C[wt][1][reg], 0.f);
          float dd = v1 - v2; side += dd * dd;
          pk[reg] = (f16)(0.5f * (v1 + v2));
        }
        int col = wt*16 + 4*q;
        *(f16x4*)&Hb[(r << 6) + ((((col >> 3) ^ (r & 7)) << 3) | (col & 7))] = pk;
      }
    } else if (mode == 2){
      #pragma unroll
      for (int wt = 0; wt < 3; wt++){
        float wa[4] = {wc1r[wt].x, wc1r[wt].y, wc1r[wt].z, wc1r[wt].w};
        #pragma unroll
        for (int reg = 0; reg < 4; reg++)
          ef[wt][reg] = C[wt][0][reg] + aL * wa[reg];   // no relu
      }
    } else {
      #pragma unroll
      for (int wt = 0; wt < 3; wt++){
        float av[4] = {wcA[wt].x, wcA[wt].y, wcA[wt].z, wcA[wt].w};
        float bv[4] = {wcB[wt].x, wcB[wt].y, wcB[wt].z, wcB[wt].w};
        #pragma unroll
        for (int reg = 0; reg < 4; reg++){
          float v1 = fmaxf(C[wt][0][reg], 0.f);
          float v2 = fmaxf(C[wt][1][reg], 0.f);
          float dd = v1 - v2; side += dd * dd;
          float fe = 0.5f * (v1 + v2);
          outAcc += fe * av[reg] + ef[wt][reg] * bv[reg];
        }
      }
    }
  };

  // ================= conv1 (EdgeConv1 on x1) =================
  stage_x(x1);
  stage_w(e1w0, 32, &Wp[0]);
  for (int l = 0; l < 5; l++) stage_w(e1wh + l*2304, 48, &Wp[(1 + l) * 3072]);
  stage_w(e1wc, 48, &Wp[6 * 3072]);     // rows k=0..47 only; action row handled per-lane
  // bias pane: [0]=e1b0 [48..287]=e1bh [288]=e1bc [336]=e2b0 [384..623]=e2bh
  for (int i = t; i < 48;  i += 256) biasP[i]       = e1b0[i];
  for (int i = t; i < 240; i += 256) biasP[48 + i]  = e1bh[i];
  for (int i = t; i < 48;  i += 256) biasP[288 + i] = e1bc[i];
  for (int i = t; i < 48;  i += 256) biasP[336 + i] = e2b0[i];
  for (int i = t; i < 240; i += 256) biasP[384 + i] = e2bh[i];
  __syncthreads();

  layer(0, 0, 1, 0);                                   // K=32 input layer
  for (int l = 1; l <= 4; l++) layer(l, 48 + (l-1)*48, 2, 0);
  layer(5, 240, 2, 1);                                 // last hidden: fe + side
  layer(6, 288, 2, 2);                                 // combine -> ef (regs)
  __syncthreads();                                     // all reads of Wp/Hb done

  // ================= conv2 (EdgeConv2 on x2) =================
  stage_x(x2);
  stage_w(e2w0, 32, &Wp[0]);
  for (int l = 0; l < 5; l++) stage_w(e2wh + l*2304, 48, &Wp[(1 + l) * 3072]);
  __syncthreads();

  layer(0, 336, 1, 0);
  for (int l = 1; l <= 4; l++) layer(l, 384 + (l-1)*48, 2, 0);
  layer(5, 576, 2, 3);                                 // fe2 + side + out dot

  // ================= epilogue =================
  outAcc += __shfl_xor(outAcc, 16);                    // reduce across quads (channels)
  outAcc += __shfl_xor(outAcc, 32);
  if (lane < 16) out[eL] = outAcc + bc2v;

  float sv = side;
  #pragma unroll
  for (int off = 32; off; off >>= 1) sv += __shfl_down(sv, off);
  if (lane == 0) atomicAdd(slacc, sv);
}

// each (edge,channel) counted once per conv: loss = S/(2*48*E)
__global__ void fin_sl(const float* __restrict__ slacc, float* __restrict__ out){
  if (threadIdx.x == 0 && blockIdx.x == 0)
    out[NEDGES] = slacc[0] * (1.0f / 57600000.0f);
}

// ================= launch ==================
extern "C" void kernel_launch(void* const* d_in, const int* in_sizes, int n_in,
                              void* d_out, int out_size, void* d_ws, size_t ws_size,
                              hipStream_t stream)
{
  if (n_in < 25) return;

  const float* nf  = (const float*)d_in[0];
  const int*   ei  = (const int*)d_in[1];
  const float* ang = (const float*)d_in[2];
  const float* act = (const float*)d_in[4];
  const float* nc1_w0 = (const float*)d_in[5];
  const float* nc1_b0 = (const float*)d_in[6];
  const float* nc1_wh = (const float*)d_in[7];
  const float* nc1_bh = (const float*)d_in[8];
  const float* nc2_w0 = (const float*)d_in[9];
  const float* nc2_b0 = (const float*)d_in[10];
  const float* nc2_wh = (const float*)d_in[11];
  const float* nc2_bh = (const float*)d_in[12];
  const float* e1w0 = (const float*)d_in[13];
  const float* e1b0 = (const float*)d_in[14];
  const float* e1wh = (const float*)d_in[15];
  const float* e1bh = (const float*)d_in[16];
  const float* e1wc = (const float*)d_in[17];
  const float* e1bc = (const float*)d_in[18];
  const float* e2w0 = (const float*)d_in[19];
  const float* e2b0 = (const float*)d_in[20];
  const float* e2wh = (const float*)d_in[21];
  const float* e2bh = (const float*)d_in[22];
  const float* e2wc = (const float*)d_in[23];
  const float* e2bc = (const float*)d_in[24];

  float* ws  = (float*)d_ws;
  float* out = (float*)d_out;
  const int eb  = (NEDGES + 255) / 256;        // 2344
  const int ecb = NEDGES / 64;                 // 9375, exact
  const int nb4 = (NNODES * 4 + 255) / 256;    // 1563

  if (ws_size >= (size_t)WS_CSR_FLOATS * sizeof(float)){
    float* x1 = ws + OX1;
    float* x2 = ws + OX2;
    int* rowptr = (int*)(ws + OROW);
    int* deg    = (int*)(ws + ODEG);
    int* perm   = (int*)(ws + OPERM);
    float* sl   = ws + OSL;

    (void)hipMemsetAsync(deg, 0, (size_t)NNODES * sizeof(int), stream);
    (void)hipMemsetAsync(sl, 0, sizeof(float), stream);

    hipLaunchKernelGGL(count_deg, dim3(eb), dim3(256), 0, stream, ei, deg);
    hipLaunchKernelGGL(scan_deg, dim3(1), dim3(1024), 0, stream, deg, rowptr);
    (void)hipMemsetAsync(deg, 0, (size_t)NNODES * sizeof(int), stream);
    hipLaunchKernelGGL(scatter_perm, dim3(eb), dim3(256), 0, stream, ei, rowptr, deg, perm);

    hipLaunchKernelGGL(nc_csr4, dim3(nb4), dim3(256), 0, stream,
        nf, ei, ang, rowptr, perm, nc1_w0, nc1_b0, nc1_wh, nc1_bh, x1);
    hipLaunchKernelGGL(nc_csr4, dim3(nb4), dim3(256), 0, stream,
        x1, ei, ang, rowptr, perm, nc2_w0, nc2_b0, nc2_wh, nc2_bh, x2);

    hipLaunchKernelGGL(ec_mfma, dim3(ecb), dim3(256), 0, stream,
        x1, x2, ei, act,
        e1w0, e1b0, e1wh, e1bh, e1wc, e1bc,
        e2w0, e2b0, e2wh, e2bh, e2wc, e2bc,
        out, sl);
    hipLaunchKernelGGL(fin_sl, dim3(1), dim3(64), 0, stream, sl, out);
  } else if (ws_size >= (size_t)WS_ATOM_FLOATS * sizeof(float)){
    float* x1  = ws + OX1;
    float* x2  = ws + OX2;
    float* cnt = ws + FCNT;
    float* sl  = ws + FSL;
    const int nb = (NNODES * CC + 255) / 256;

    (void)hipMemsetAsync(ws, 0, (size_t)WS_ATOM_FLOATS * sizeof(float), stream);
    hipLaunchKernelGGL(nc_kernel, dim3(eb), dim3(256), 0, stream,
        nf, ei, ang, nc1_w0, nc1_b0, nc1_wh, nc1_bh, x1, cnt);
    hipLaunchKernelGGL(node_fin, dim3(nb), dim3(256), 0, stream, x1, cnt);
    (void)hipMemsetAsync(cnt, 0, (size_t)NNODES * sizeof(float), stream);
    hipLaunchKernelGGL(nc_kernel, dim3(eb), dim3(256), 0, stream,
        x1, ei, ang, nc2_w0, nc2_b0, nc2_wh, nc2_bh, x2, cnt);
    hipLaunchKernelGGL(node_fin, dim3(nb), dim3(256), 0, stream, x2, cnt);
    hipLaunchKernelGGL(ec_mfma, dim3(ecb), dim3(256), 0, stream,
        x1, x2, ei, act,
        e1w0, e1b0, e1wh, e1bh, e1wc, e1bc,
        e2w0, e2b0, e2wh, e2bh, e2wc, e2bc,
        out, sl);
    hipLaunchKernelGGL(fin_sl, dim3(1), dim3(64), 0, stream, sl, out);
  }
}

// Round 13
// 1029.639 us; speedup vs baseline: 1.2386x; 1.0868x over previous
//
#include <hip/hip_runtime.h>

typedef unsigned int u32;
typedef _Float16 f16;
typedef __attribute__((ext_vector_type(8))) _Float16 f16x8;
typedef __attribute__((ext_vector_type(4))) _Float16 f16x4;
typedef __attribute__((ext_vector_type(4))) float f32x4;

#define NNODES 100000
#define NEDGES 600000
#define CC 16
#define HH 48
#define NL 5

// ---- CSR ws layout (float-sized units), total 4,000,064 floats = 16.0 MB ----
#define OX1   0
#define OX2   1600000
#define OROW  3200000
#define ODEG  3300032          // deg during CSR build; ALIASED as W-frag pane after
#define OGF   3300032          // 19,968 floats (39,936 f16) W fragments
#define OPERM 3400032
#define OSL   4000032
#define WS_CSR_FLOATS    4000064
// ---- fallback (atomic) layout ----
#define FCNT  3200000
#define FSL   3300000
#define OGFA  3300064
#define WS_ATOM_FLOATS   3320064

// =================== CSR build ===================
__global__ __launch_bounds__(256) void count_deg(const int* __restrict__ ei, int* __restrict__ deg){
  int e = blockIdx.x * 256 + threadIdx.x;
  if (e >= NEDGES) return;
  atomicAdd(&deg[ei[NEDGES + e]], 1);
}

__global__ __launch_bounds__(1024) void scan_deg(const int* __restrict__ deg, int* __restrict__ rowptr){
  __shared__ int part[1024];
  int t = threadIdx.x;
  const int CH = (NNODES + 1023) / 1024;
  int b = t * CH;
  int e = b + CH < NNODES ? b + CH : NNODES;
  int s = 0;
  for (int i = b; i < e; i++) s += deg[i];
  part[t] = s;
  __syncthreads();
  for (int off = 1; off < 1024; off <<= 1){
    int v = (t >= off) ? part[t - off] : 0;
    __syncthreads();
    part[t] += v;
    __syncthreads();
  }
  int run = (t == 0) ? 0 : part[t - 1];
  for (int i = b; i < e; i++){ rowptr[i] = run; run += deg[i]; }
  if (t == 1023) rowptr[NNODES] = run;
}

__global__ __launch_bounds__(256) void scatter_perm(const int* __restrict__ ei,
    const int* __restrict__ rowptr, int* __restrict__ deg2, int* __restrict__ perm){
  int e = blockIdx.x * 256 + threadIdx.x;
  if (e >= NEDGES) return;
  int d = ei[NEDGES + e];
  int pos = rowptr[d] + atomicAdd(&deg2[d], 1);
  perm[pos] = e;
}

// ============ W-fragment precompute: one f16x8 A-frag per (layer,ks,wt,lane) ============
// lay 0..6 = EC1 (w0 K32, wh0..4 K48, wc K48-of-49); 7..12 = EC2 (w0, wh0..4).
// gf[((lay*2+ks)*3+wt)*512 + lane*8 + j] = w[(ks*32 + (lane>>4)*8 + j)*48 + wt*16 + (lane&15)]
__global__ __launch_bounds__(256) void prep_wfrag(
    const float* __restrict__ e1w0, const float* __restrict__ e1wh, const float* __restrict__ e1wc,
    const float* __restrict__ e2w0, const float* __restrict__ e2wh, f16* __restrict__ gf)
{
  int idx = blockIdx.x * 256 + threadIdx.x;
  if (idx >= 39936) return;
  int j = idx & 7, lane = (idx >> 3) & 63, f = idx >> 9;
  int wt = f % 3, ksl = f / 3;
  int ks = ksl & 1, lay = ksl >> 1;
  int k = ks * 32 + ((lane >> 4) << 3) + j;
  int m = wt * 16 + (lane & 15);
  const float* w; int Kl;
  if (lay == 0){ w = e1w0; Kl = 32; }
  else if (lay <= 5){ w = e1wh + (lay - 1) * 2304; Kl = 48; }
  else if (lay == 6){ w = e1wc; Kl = 48; }
  else if (lay == 7){ w = e2w0; Kl = 32; }
  else { w = e2wh + (lay - 8) * 2304; Kl = 48; }
  gf[idx] = (k < Kl) ? (f16)w[k * 48 + m] : (f16)0.f;
}

// ====== NodeConv: 4 threads per node stride its CSR edges; shfl-reduce; no atomics ======
__global__ __launch_bounds__(256) void nc_csr4(
    const float* __restrict__ x, const int* __restrict__ ei,
    const float* __restrict__ ang,
    const int* __restrict__ rowptr, const int* __restrict__ perm,
    const float* __restrict__ w0, const float* __restrict__ b0,
    const float* __restrict__ wh, const float* __restrict__ bh,
    float* __restrict__ xout)
{
  int tid = blockIdx.x * 256 + threadIdx.x;
  int n = tid >> 2, j = tid & 3;
  if (n >= NNODES) return;
  int beg = rowptr[n], end = rowptr[n + 1];

  float xd[16];
  {
    const float4* pd = (const float4*)(x + (long)n * 16);
    #pragma unroll
    for (int i = 0; i < 4; i++){ float4 v = pd[i]; xd[4*i]=v.x; xd[4*i+1]=v.y; xd[4*i+2]=v.z; xd[4*i+3]=v.w; }
  }
  float p0[16];
  #pragma unroll
  for (int jj = 0; jj < 16; jj++) p0[jj] = b0[jj];
  #pragma unroll
  for (int k = 0; k < 16; k++){
    float v = xd[k];
    #pragma unroll
    for (int jj = 0; jj < 16; jj++) p0[jj] = fmaf(v, w0[k*16 + jj], p0[jj]);
  }

  float sum[16];
  #pragma unroll
  for (int jj = 0; jj < 16; jj++) sum[jj] = 0.f;

  for (int idx = beg + j; idx < end; idx += 4){
    int e = perm[idx];
    int s = ei[e];
    float a_ = ang[e];
    float xs[16];
    {
      const float4* ps = (const float4*)(x + (long)s * 16);
      #pragma unroll
      for (int i = 0; i < 4; i++){ float4 v = ps[i]; xs[4*i]=v.x; xs[4*i+1]=v.y; xs[4*i+2]=v.z; xs[4*i+3]=v.w; }
    }
    float acc[16], h[16];
    #pragma unroll
    for (int jj = 0; jj < 16; jj++) acc[jj] = p0[jj];
    #pragma unroll
    for (int k = 0; k < 16; k++){
      float v = xs[k];
      #pragma unroll
      for (int jj = 0; jj < 16; jj++) acc[jj] = fmaf(v, w0[(16 + k)*16 + jj], acc[jj]);
    }
    #pragma unroll
    for (int jj = 0; jj < 16; jj++) h[jj] = fmaxf(fmaf(a_, w0[32*16 + jj], acc[jj]), 0.f);

    for (int l = 0; l < NL; l++){
      const float* w = wh + l * 256;
      const float* b = bh + l * 16;
      #pragma unroll
      for (int jj = 0; jj < 16; jj++) acc[jj] = b[jj];
      #pragma unroll
      for (int k = 0; k < 16; k++){
        float v = h[k];
        #pragma unroll
        for (int jj = 0; jj < 16; jj++) acc[jj] = fmaf(v, w[k*16 + jj], acc[jj]);
      }
      #pragma unroll
      for (int jj = 0; jj < 16; jj++) h[jj] = fmaxf(acc[jj], 0.f);
    }
    #pragma unroll
    for (int jj = 0; jj < 16; jj++) sum[jj] += h[jj];
  }

  #pragma unroll
  for (int jj = 0; jj < 16; jj++){
    sum[jj] += __shfl_xor(sum[jj], 1);
    sum[jj] += __shfl_xor(sum[jj], 2);
  }
  if (j == 0){
    float inv = 1.f / fmaxf((float)(end - beg), 1.f);
    float4* po = (float4*)(xout + (long)n * 16);
    #pragma unroll
    for (int i = 0; i < 4; i++){
      float4 v; v.x = sum[4*i]*inv; v.y = sum[4*i+1]*inv; v.z = sum[4*i+2]*inv; v.w = sum[4*i+3]*inv;
      po[i] = v;
    }
  }
}

// =================== fallback atomic NodeConv (r7, proven) ===================
__global__ __launch_bounds__(256) void nc_kernel(
    const float* __restrict__ x, const int* __restrict__ ei,
    const float* __restrict__ ang,
    const float* __restrict__ w0, const float* __restrict__ b0,
    const float* __restrict__ wh, const float* __restrict__ bh,
    float* __restrict__ agg, float* __restrict__ cnt)
{
  int e = blockIdx.x * 256 + threadIdx.x;
  if (e >= NEDGES) return;
  int s = ei[e];
  int d = ei[NEDGES + e];
  float in[33];
  {
    const float4* pd = (const float4*)(x + (long)d * 16);
    const float4* ps = (const float4*)(x + (long)s * 16);
    #pragma unroll
    for (int i = 0; i < 4; i++){ float4 v = pd[i]; in[4*i]=v.x; in[4*i+1]=v.y; in[4*i+2]=v.z; in[4*i+3]=v.w; }
    #pragma unroll
    for (int i = 0; i < 4; i++){ float4 v = ps[i]; in[16+4*i]=v.x; in[16+4*i+1]=v.y; in[16+4*i+2]=v.z; in[16+4*i+3]=v.w; }
  }
  in[32] = ang[e];
  float h[16], acc[16];
  #pragma unroll
  for (int j = 0; j < 16; j++) acc[j] = b0[j];
  #pragma unroll
  for (int k = 0; k < 33; k++){
    float v = in[k];
    #pragma unroll
    for (int j = 0; j < 16; j++) acc[j] = fmaf(v, w0[k*16+j], acc[j]);
  }
  #pragma unroll
  for (int j = 0; j < 16; j++) h[j] = fmaxf(acc[j], 0.f);
  for (int l = 0; l < NL; l++){
    const float* w = wh + l * 256;
    const float* b = bh + l * 16;
    #pragma unroll
    for (int j = 0; j < 16; j++) acc[j] = b[j];
    #pragma unroll
    for (int k = 0; k < 16; k++){
      float v = h[k];
      #pragma unroll
      for (int j = 0; j < 16; j++) acc[j] = fmaf(v, w[k*16+j], acc[j]);
    }
    #pragma unroll
    for (int j = 0; j < 16; j++) h[j] = fmaxf(acc[j], 0.f);
  }
  float* ag = agg + (long)d * 16;
  #pragma unroll
  for (int j = 0; j < 16; j++) atomicAdd(ag + j, h[j]);
  atomicAdd(cnt + d, 1.0f);
}

__global__ __launch_bounds__(256) void node_fin(float* __restrict__ x, const float* __restrict__ cnt)
{
  int i = blockIdx.x * 256 + threadIdx.x;
  if (i >= NNODES * CC) return;
  float c = cnt[i >> 4];
  x[i] = x[i] / fmaxf(c, 1.f);
}

// ============================================================================
// Fused EdgeConv1+EdgeConv2, MFMA v3: W-fragments direct from global (precomputed,
// L2-broadcast), bias direct from global. LDS = H only (16384 B). Barriers: 3.
// Tile = 64 edges (f1 rows 0..63, f2 rows 64..127); wave w owns rows wv*16±64.
// A = W (m=channel), B = H (n=edge): D[row=4q+reg]=channel, D[col=lane&15]=edge.
// H swizzle (r11/r12-proven): elem (row,k) -> row*64 + ((k/8 ^ row%8)*8 | k%8).
// ============================================================================
__global__ __launch_bounds__(256) void ec_mfma(
    const float* __restrict__ x1, const float* __restrict__ x2,
    const int* __restrict__ ei, const float* __restrict__ act,
    const f16* __restrict__ gf,
    const float* __restrict__ e1wc, const float* __restrict__ e1b0,
    const float* __restrict__ e1bh, const float* __restrict__ e1bc,
    const float* __restrict__ e2b0, const float* __restrict__ e2bh,
    const float* __restrict__ e2wc, const float* __restrict__ e2bc,
    float* __restrict__ out, float* __restrict__ slacc)
{
  __shared__ __align__(16) f16 Hb[128 * 64];      // 16384 B

  const int t = threadIdx.x;
  const int lane = t & 63;
  const int wv = t >> 6;
  const int q = lane >> 4, n15 = lane & 15;
  const int ebase = blockIdx.x * 64;
  const int eL = ebase + wv * 16 + n15;

  const float aL = act[eL];
  const float bc2v = e2bc[0];
  float4 wc1r[3], wcA[3], wcB[3];
  #pragma unroll
  for (int wt = 0; wt < 3; wt++){
    wc1r[wt] = *(const float4*)&e1wc[2304 + wt*16 + 4*q];   // wc1 action row 48
    wcA[wt]  = *(const float4*)&e2wc[wt*16 + 4*q];          // wc2[0:48]
    wcB[wt]  = *(const float4*)&e2wc[48 + wt*16 + 4*q];     // wc2[48:96]
  }

  // ---- staging: H rows (2 threads/row; zero cols 48..63) ----
  auto stage_x = [&](const float* x){
    int row = t >> 1, half = t & 1;
    int eb = ebase + (row & 63);
    int s = ei[eb], dn = ei[NEDGES + eb];
    int node = ((half ^ (row >> 6)) & 1) ? s : dn;  // f1=[x_d|x_s], f2=[x_s|x_d]
    const float4* p = (const float4*)(x + (long)node * 16);
    float4 v0 = p[0], v1 = p[1], v2 = p[2], v3 = p[3];
    f16* hp = &Hb[row << 6];
    int rs = row & 7;
    f16x8 h;
    h[0]=(f16)v0.x; h[1]=(f16)v0.y; h[2]=(f16)v0.z; h[3]=(f16)v0.w;
    h[4]=(f16)v1.x; h[5]=(f16)v1.y; h[6]=(f16)v1.z; h[7]=(f16)v1.w;
    *(f16x8*)&hp[((2*half) ^ rs) << 3] = h;
    h[0]=(f16)v2.x; h[1]=(f16)v2.y; h[2]=(f16)v2.z; h[3]=(f16)v2.w;
    h[4]=(f16)v3.x; h[5]=(f16)v3.y; h[6]=(f16)v3.z; h[7]=(f16)v3.w;
    *(f16x8*)&hp[((2*half + 1) ^ rs) << 3] = h;
    if (half){
      f16x8 z = {};
      *(f16x8*)&hp[(6 ^ rs) << 3] = z;
      *(f16x8*)&hp[(7 ^ rs) << 3] = z;
    }
  };

  float ef[3][4];
  float side = 0.f;
  float outAcc = 0.f;

  // mode 0: hidden(relu->H). 1: EC1-final(relu,fe+side->H f1 rows).
  // 2: combine(no relu, ef=C+act*wc1r). 3: EC2-final(relu,fe2+side,out dot).
  auto layer = [&](int lay, const float* bias, int nks, int mode){
    const int nEt = (mode == 2) ? 1 : 2;
    f32x4 C[3][2];
    #pragma unroll
    for (int wt = 0; wt < 3; wt++){
      float4 b4 = *(const float4*)&bias[wt*16 + 4*q];
      C[wt][0] = (f32x4){b4.x, b4.y, b4.z, b4.w};
      C[wt][1] = C[wt][0];
    }
    for (int ks = 0; ks < nks; ks++){
      int c = ks*4 + q;
      f16x8 Af[3];
      #pragma unroll
      for (int wt = 0; wt < 3; wt++)
        Af[wt] = *(const f16x8*)&gf[((((lay*2 + ks)*3) + wt) << 9) + (lane << 3)];
      for (int et = 0; et < nEt; et++){
        int r = (et << 6) + wv*16 + n15;
        f16x8 Bf = *(const f16x8*)&Hb[(r << 6) + ((c ^ (r & 7)) << 3)];
        #pragma unroll
        for (int wt = 0; wt < 3; wt++)
          C[wt][et] = __builtin_amdgcn_mfma_f32_16x16x32_f16(Af[wt], Bf, C[wt][et], 0, 0, 0);
      }
    }
    if (mode == 0){
      #pragma unroll
      for (int et = 0; et < 2; et++){
        int r = (et << 6) + wv*16 + n15;
        #pragma unroll
        for (int wt = 0; wt < 3; wt++){
          f16x4 pk;
          #pragma unroll
          for (int reg = 0; reg < 4; reg++) pk[reg] = (f16)fmaxf(C[wt][et][reg], 0.f);
          int col = wt*16 + 4*q;
          *(f16x4*)&Hb[(r << 6) + ((((col >> 3) ^ (r & 7)) << 3) | (col & 7))] = pk;
        }
      }
    } else if (mode == 1){
      int r = wv*16 + n15;
      #pragma unroll
      for (int wt = 0; wt < 3; wt++){
        f16x4 pk;
        #pragma unroll
        for (int reg = 0; reg < 4; reg++){
          float v1 = fmaxf(C[wt][0][reg], 0.f);
          float v2 = fmaxf(C[wt][1][reg], 0.f);
          float dd = v1 - v2; side += dd * dd;
          pk[reg] = (f16)(0.5f * (v1 + v2));
        }
        int col = wt*16 + 4*q;
        *(f16x4*)&Hb[(r << 6) + ((((col >> 3) ^ (r & 7)) << 3) | (col & 7))] = pk;
      }
    } else if (mode == 2){
      #pragma unroll
      for (int wt = 0; wt < 3; wt++){
        float wa[4] = {wc1r[wt].x, wc1r[wt].y, wc1r[wt].z, wc1r[wt].w};
        #pragma unroll
        for (int reg = 0; reg < 4; reg++)
          ef[wt][reg] = C[wt][0][reg] + aL * wa[reg];
      }
    } else {
      #pragma unroll
      for (int wt = 0; wt < 3; wt++){
        float av[4] = {wcA[wt].x, wcA[wt].y, wcA[wt].z, wcA[wt].w};
        float bv[4] = {wcB[wt].x, wcB[wt].y, wcB[wt].z, wcB[wt].w};
        #pragma unroll
        for (int reg = 0; reg < 4; reg++){
          float v1 = fmaxf(C[wt][0][reg], 0.f);
          float v2 = fmaxf(C[wt][1][reg], 0.f);
          float dd = v1 - v2; side += dd * dd;
          float fe = 0.5f * (v1 + v2);
          outAcc += fe * av[reg] + ef[wt][reg] * bv[reg];
        }
      }
    }
  };

  // ================= EdgeConv1 on x1 =================
  stage_x(x1);
  __syncthreads();
  layer(0, e1b0, 1, 0);
  layer(1, e1bh + 0*48, 2, 0);
  layer(2, e1bh + 1*48, 2, 0);
  layer(3, e1bh + 2*48, 2, 0);
  layer(4, e1bh + 3*48, 2, 0);
  layer(5, e1bh + 4*48, 2, 1);      // last hidden: fe + side -> f1 rows
  layer(6, e1bc, 2, 2);             // combine -> ef (regs)
  __syncthreads();

  // ================= EdgeConv2 on x2 =================
  stage_x(x2);
  __syncthreads();
  layer(7,  e2b0, 1, 0);
  layer(8,  e2bh + 0*48, 2, 0);
  layer(9,  e2bh + 1*48, 2, 0);
  layer(10, e2bh + 2*48, 2, 0);
  layer(11, e2bh + 3*48, 2, 0);
  layer(12, e2bh + 4*48, 2, 3);     // fe2 + side + out dot

  // ================= epilogue =================
  outAcc += __shfl_xor(outAcc, 16);
  outAcc += __shfl_xor(outAcc, 32);
  if (lane < 16) out[eL] = outAcc + bc2v;

  float sv = side;
  #pragma unroll
  for (int off = 32; off; off >>= 1) sv += __shfl_down(sv, off);
  if (lane == 0) atomicAdd(slacc, sv);
}

// each (edge,channel) counted once per conv: loss = S/(2*48*E)
__global__ void fin_sl(const float* __restrict__ slacc, float* __restrict__ out){
  if (threadIdx.x == 0 && blockIdx.x == 0)
    out[NEDGES] = slacc[0] * (1.0f / 57600000.0f);
}

// ================= launch ==================
extern "C" void kernel_launch(void* const* d_in, const int* in_sizes, int n_in,
                              void* d_out, int out_size, void* d_ws, size_t ws_size,
                              hipStream_t stream)
{
  if (n_in < 25) return;

  const float* nf  = (const float*)d_in[0];
  const int*   ei  = (const int*)d_in[1];
  const float* ang = (const float*)d_in[2];
  const float* act = (const float*)d_in[4];
  const float* nc1_w0 = (const float*)d_in[5];
  const float* nc1_b0 = (const float*)d_in[6];
  const float* nc1_wh = (const float*)d_in[7];
  const float* nc1_bh = (const float*)d_in[8];
  const float* nc2_w0 = (const float*)d_in[9];
  const float* nc2_b0 = (const float*)d_in[10];
  const float* nc2_wh = (const float*)d_in[11];
  const float* nc2_bh = (const float*)d_in[12];
  const float* e1w0 = (const float*)d_in[13];
  const float* e1b0 = (const float*)d_in[14];
  const float* e1wh = (const float*)d_in[15];
  const float* e1bh = (const float*)d_in[16];
  const float* e1wc = (const float*)d_in[17];
  const float* e1bc = (const float*)d_in[18];
  const float* e2w0 = (const float*)d_in[19];
  const float* e2b0 = (const float*)d_in[20];
  const float* e2wh = (const float*)d_in[21];
  const float* e2bh = (const float*)d_in[22];
  const float* e2wc = (const float*)d_in[23];
  const float* e2bc = (const float*)d_in[24];

  float* ws  = (float*)d_ws;
  float* out = (float*)d_out;
  const int eb  = (NEDGES + 255) / 256;        // 2344
  const int ecb = NEDGES / 64;                 // 9375, exact
  const int nb4 = (NNODES * 4 + 255) / 256;    // 1563
  const int pfb = (39936 + 255) / 256;         // 156

  if (ws_size >= (size_t)WS_CSR_FLOATS * sizeof(float)){
    float* x1 = ws + OX1;
    float* x2 = ws + OX2;
    int* rowptr = (int*)(ws + OROW);
    int* deg    = (int*)(ws + ODEG);
    int* perm   = (int*)(ws + OPERM);
    f16* gf     = (f16*)(ws + OGF);            // aliases deg (dead after scatter)
    float* sl   = ws + OSL;

    (void)hipMemsetAsync(deg, 0, (size_t)NNODES * sizeof(int), stream);
    (void)hipMemsetAsync(sl, 0, sizeof(float), stream);

    hipLaunchKernelGGL(count_deg, dim3(eb), dim3(256), 0, stream, ei, deg);
    hipLaunchKernelGGL(scan_deg, dim3(1), dim3(1024), 0, stream, deg, rowptr);
    (void)hipMemsetAsync(deg, 0, (size_t)NNODES * sizeof(int), stream);
    hipLaunchKernelGGL(scatter_perm, dim3(eb), dim3(256), 0, stream, ei, rowptr, deg, perm);

    // deg is dead now: overwrite with W fragments
    hipLaunchKernelGGL(prep_wfrag, dim3(pfb), dim3(256), 0, stream,
        e1w0, e1wh, e1wc, e2w0, e2wh, gf);

    hipLaunchKernelGGL(nc_csr4, dim3(nb4), dim3(256), 0, stream,
        nf, ei, ang, rowptr, perm, nc1_w0, nc1_b0, nc1_wh, nc1_bh, x1);
    hipLaunchKernelGGL(nc_csr4, dim3(nb4), dim3(256), 0, stream,
        x1, ei, ang, rowptr, perm, nc2_w0, nc2_b0, nc2_wh, nc2_bh, x2);

    hipLaunchKernelGGL(ec_mfma, dim3(ecb), dim3(256), 0, stream,
        x1, x2, ei, act, gf,
        e1wc, e1b0, e1bh, e1bc, e2b0, e2bh, e2wc, e2bc,
        out, sl);
    hipLaunchKernelGGL(fin_sl, dim3(1), dim3(64), 0, stream, sl, out);
  } else if (ws_size >= (size_t)WS_ATOM_FLOATS * sizeof(float)){
    float* x1  = ws + OX1;
    float* x2  = ws + OX2;
    float* cnt = ws + FCNT;
    float* sl  = ws + FSL;
    f16* gf    = (f16*)(ws + OGFA);
    const int nb = (NNODES * CC + 255) / 256;

    (void)hipMemsetAsync(ws, 0, (size_t)WS_ATOM_FLOATS * sizeof(float), stream);
    hipLaunchKernelGGL(prep_wfrag, dim3(pfb), dim3(256), 0, stream,
        e1w0, e1wh, e1wc, e2w0, e2wh, gf);
    hipLaunchKernelGGL(nc_kernel, dim3(eb), dim3(256), 0, stream,
        nf, ei, ang, nc1_w0, nc1_b0, nc1_wh, nc1_bh, x1, cnt);
    hipLaunchKernelGGL(node_fin, dim3(nb), dim3(256), 0, stream, x1, cnt);
    (void)hipMemsetAsync(cnt, 0, (size_t)NNODES * sizeof(float), stream);
    hipLaunchKernelGGL(nc_kernel, dim3(eb), dim3(256), 0, stream,
        x1, ei, ang, nc2_w0, nc2_b0, nc2_wh, nc2_bh, x2, cnt);
    hipLaunchKernelGGL(node_fin, dim3(nb), dim3(256), 0, stream, x2, cnt);
    hipLaunchKernelGGL(ec_mfma, dim3(ecb), dim3(256), 0, stream,
        x1, x2, ei, act, gf,
        e1wc, e1b0, e1bh, e1bc, e2b0, e2bh, e2wc, e2bc,
        out, sl);
    hipLaunchKernelGGL(fin_sl, dim3(1), dim3(64), 0, stream, sl, out);
  }
}